// Round 12
// baseline (834.815 us; speedup 1.0000x reference)
//
#include <hip/hip_runtime.h>
#include <stdint.h>

#define NN   8192
#define DIN  256
#define FF   128
#define NF   (NN*FF)          // 1048576
#define SLOPE 0.2f
#define EPSI  1e-5f
#define NCHUNK 16             // split-K chunks over n

typedef float vf4 __attribute__((ext_vector_type(4)));
typedef short bf16x8 __attribute__((ext_vector_type(8)));
typedef float f32x4 __attribute__((ext_vector_type(4)));

// ---- workspace layout (float offsets) ----
#define OFF_PROJ   0                       // [2][N][F] f32 (k_gemm->k_sprep), then REUSED as bitmask [N][256] u32 (8 MB)
#define OFF_RESID  (2*NF)                  // [N][F] f32
#define OFF_PACKED (3*NF)                  // [N][F] u32: lo16=bf16(h0), hi16=bf16(h1)
#define OFF_SS     (4*NF)                  // s_src [2][N]
#define OFF_ST     (OFF_SS + 2*NN)         // s_tgt [2][N]
#define OFF_CSUM   (OFF_ST + 2*NN)         // colsum [2][N]
#define OFF_STATS  (OFF_CSUM + 2*NN)       // S, SS (padded to 16)
#define OFF_NTAB   (OFF_STATS + 16)        // float4[N] = {st0, st1, rcp0, rcp1}
#define OFF_VALS   (OFF_NTAB + 4*NN)       // [N][F] f32
#define OFF_WT     (OFF_VALS + NF)         // W_res^T [DIN][F]
#define OFF_PT2    (OFF_WT + DIN*FF)       // packedT2: [N/32][2][128][16] u32 (4 MB)
#define OFF_VPART  (OFF_PT2 + NF)          // vpart: [NCHUNK][N][F] f32 (64 MB)

__device__ __forceinline__ float lrelu(float x) { return x >= 0.f ? x : SLOPE * x; }

__device__ __forceinline__ uint32_t bfpack(float a, float b) {
  uint32_t ua = __float_as_uint(a); ua += 0x7fffu + ((ua >> 16) & 1u);
  uint32_t ub = __float_as_uint(b); ub += 0x7fffu + ((ub >> 16) & 1u);
  return (ua >> 16) | (ub & 0xffff0000u);
}

// ---- K0: transpose W_res [F][DIN] -> Wt [DIN][F] ----
__global__ __launch_bounds__(256) void k_wt(const float* __restrict__ wres, float* __restrict__ wt) {
  int i = blockIdx.x * 256 + threadIdx.x;
  int d = i >> 7, f = i & 127;
  wt[i] = wres[f * DIN + d];
}

// ---- K1: 3 GEMMs M=8192 K=256 N=128 (heads 0,1 -> proj; y==2 -> resid) ----
__global__ __launch_bounds__(256) void k_gemm(const float* __restrict__ x, const float* __restrict__ Wh,
                                              const float* __restrict__ wt, float* __restrict__ proj,
                                              float* __restrict__ resid) {
  const int h = blockIdx.y;
  const float* __restrict__ Wsrc = (h < 2) ? (Wh + h * (DIN * FF)) : wt;
  float* __restrict__ outp = (h < 2) ? (proj + h * NF) : resid;
  const int row0 = blockIdx.x * 64;
  __shared__ float xs[64 * 68];
  const int tid = threadIdx.x;
  const int ft = tid & 15, rt = tid >> 4;
  const int f0 = ft * 8, r0 = rt * 4;
  float acc[4][8];
#pragma unroll
  for (int j = 0; j < 4; ++j)
#pragma unroll
    for (int k = 0; k < 8; ++k) acc[j][k] = 0.f;

  for (int kc = 0; kc < 4; ++kc) {
    const int d0 = kc * 64;
#pragma unroll
    for (int k2 = 0; k2 < 4; ++k2) {
      int i = tid * 4 + k2 * 1024;
      int r = i >> 6, dd = i & 63;
      *(float4*)&xs[r * 68 + dd] = *(const float4*)&x[(row0 + r) * DIN + d0 + dd];
    }
    __syncthreads();
#pragma unroll
    for (int g = 0; g < 16; ++g) {
      const int dd = g * 4;
      float xr[4][4];
#pragma unroll
      for (int j = 0; j < 4; ++j) {
        float4 t = *(const float4*)&xs[(r0 + j) * 68 + dd];
        xr[j][0] = t.x; xr[j][1] = t.y; xr[j][2] = t.z; xr[j][3] = t.w;
      }
#pragma unroll
      for (int i = 0; i < 4; ++i) {
        float4 wa = *(const float4*)&Wsrc[(d0 + dd + i) * FF + f0];
        float4 wb = *(const float4*)&Wsrc[(d0 + dd + i) * FF + f0 + 4];
#pragma unroll
        for (int j = 0; j < 4; ++j) {
          float xx = xr[j][i];
          acc[j][0] += xx * wa.x; acc[j][1] += xx * wa.y; acc[j][2] += xx * wa.z; acc[j][3] += xx * wa.w;
          acc[j][4] += xx * wb.x; acc[j][5] += xx * wb.y; acc[j][6] += xx * wb.z; acc[j][7] += xx * wb.w;
        }
      }
    }
    __syncthreads();
  }
#pragma unroll
  for (int j = 0; j < 4; ++j) {
    int row = row0 + r0 + j;
    *(float4*)&outp[row * FF + f0]     = make_float4(acc[j][0], acc[j][1], acc[j][2], acc[j][3]);
    *(float4*)&outp[row * FF + f0 + 4] = make_float4(acc[j][4], acc[j][5], acc[j][6], acc[j][7]);
  }
}

// ---- K1b: per-node dots s_src/s_tgt (both heads) + bf16 pack of proj ----
__global__ __launch_bounds__(256) void k_sprep(const float* __restrict__ proj, const float* __restrict__ a_src,
                                               const float* __restrict__ a_tgt, float* __restrict__ ss,
                                               float* __restrict__ st, uint32_t* __restrict__ packed) {
  int lane = threadIdx.x & 63, wid = threadIdx.x >> 6;
  int n = blockIdx.x * 4 + wid;
  float2 q0 = *(const float2*)&proj[n * FF + 2 * lane];
  float2 q1 = *(const float2*)&proj[NF + n * FF + 2 * lane];
  float2 as0 = *(const float2*)&a_src[2 * lane];
  float2 at0 = *(const float2*)&a_tgt[2 * lane];
  float2 as1 = *(const float2*)&a_src[FF + 2 * lane];
  float2 at1 = *(const float2*)&a_tgt[FF + 2 * lane];
  float v0 = q0.x * as0.x + q0.y * as0.y;
  float v1 = q0.x * at0.x + q0.y * at0.y;
  float v2 = q1.x * as1.x + q1.y * as1.y;
  float v3 = q1.x * at1.x + q1.y * at1.y;
#pragma unroll
  for (int o = 1; o < 64; o <<= 1) {
    v0 += __shfl_xor(v0, o); v1 += __shfl_xor(v1, o);
    v2 += __shfl_xor(v2, o); v3 += __shfl_xor(v3, o);
  }
  uint2 pk;
  pk.x = bfpack(q0.x, q1.x);
  pk.y = bfpack(q0.y, q1.y);
  *(uint2*)&packed[n * FF + 2 * lane] = pk;
  if (lane == 0) { ss[n] = v0; ss[NN + n] = v2; st[n] = v1; st[NN + n] = v3; }
}

// ---- K1c: packed[n][f] -> packedT2[n/32][h][f][n&31] bf16-pair words ----
__global__ __launch_bounds__(256) void k_tpose(const uint32_t* __restrict__ packed, uint32_t* __restrict__ pt2) {
  __shared__ uint32_t sb[32][129];
  const int t = threadIdx.x, c = blockIdx.x;
  const int nl = t >> 3, fb = (t & 7) * 16;
#pragma unroll
  for (int i = 0; i < 4; ++i) {
    uint4 v = *(const uint4*)&packed[(c * 32 + nl) * FF + fb + i * 4];
    sb[nl][fb + i * 4] = v.x; sb[nl][fb + i * 4 + 1] = v.y;
    sb[nl][fb + i * 4 + 2] = v.z; sb[nl][fb + i * 4 + 3] = v.w;
  }
  __syncthreads();
  const int h = t >> 7, f = t & 127;
  uint32_t wbuf[16];
#pragma unroll
  for (int p = 0; p < 16; ++p) {
    uint32_t a = sb[2 * p][f], b = sb[2 * p + 1][f];
    wbuf[p] = h ? ((a >> 16) | (b & 0xffff0000u)) : ((a & 0xffffu) | (b << 16));
  }
  uint32_t* dst = pt2 + ((c * 2 + h) * 128 + f) * 16;
#pragma unroll
  for (int i = 0; i < 4; ++i)
    *(uint4*)&dst[i * 4] = make_uint4(wbuf[i * 4], wbuf[i * 4 + 1], wbuf[i * 4 + 2], wbuf[i * 4 + 3]);
}

// ---- K2 (k_scan, r7-verified): copy mask -> out1, emit SORTED bitmask
// (word = m*256 + n/32, bit = n&31), colsum in registers + 2 atomics/thread. ----
__global__ __launch_bounds__(256) void k_scan(const float* __restrict__ mask, float* __restrict__ maskout,
                                              const float* __restrict__ ss, const float* __restrict__ st,
                                              float* __restrict__ csum, uint32_t* __restrict__ bitmask) {
  const int tid = threadIdx.x;
  const int lane = tid & 63, wv = tid >> 6;
  const int n = blockIdx.x * 256 + tid;
  const int m0 = blockIdx.y * 128;
  const int wbase = blockIdx.x * 8 + wv * 2;
  const float st0 = st[n], st1 = st[NN + n];
  const float ssA = ss[m0 + lane],      ssB = ss[m0 + 64 + lane];
  const float ssC = ss[NN + m0 + lane], ssD = ss[NN + m0 + 64 + lane];
  float c0 = 0.f, c1 = 0.f;

  for (int i = 0; i < 128; i += 8) {
    float v[8];
#pragma unroll
    for (int r = 0; r < 8; ++r)
      v[r] = __builtin_nontemporal_load(&mask[(size_t)(m0 + i + r) * NN + n]);
#pragma unroll
    for (int r = 0; r < 8; ++r) {
      const int m = m0 + i + r;
      __builtin_nontemporal_store(v[r], &maskout[(size_t)m * NN + n]);
      bool e = v[r] > -0.5e9f;
      unsigned long long bm = __ballot(e);
      if (lane == 0)
        *(uint2*)&bitmask[m * 256 + wbase] = make_uint2((uint32_t)bm, (uint32_t)(bm >> 32));
      const int ri = i + r;
      float s0 = __uint_as_float(__builtin_amdgcn_readlane(
                   __float_as_uint(ri < 64 ? ssA : ssB), ri & 63));
      float s1 = __uint_as_float(__builtin_amdgcn_readlane(
                   __float_as_uint(ri < 64 ? ssC : ssD), ri & 63));
      float w0 = __expf(lrelu(s0 + st0));
      float w1 = __expf(lrelu(s1 + st1));
      c0 += e ? w0 : 0.f;
      c1 += e ? w1 : 0.f;
    }
  }
  atomicAdd(&csum[n], c0);
  atomicAdd(&csum[NN + n], c1);
}

// ---- K2c: pack per-column table {st0, st1, 1/csum0, 1/csum1} ----
__global__ __launch_bounds__(256) void k_ntab(const float* __restrict__ st, const float* __restrict__ csum,
                                              float4* __restrict__ ntab) {
  int i = blockIdx.x * 256 + threadIdx.x;
  ntab[i] = make_float4(st[i], st[NN + i], 1.f / csum[i], 1.f / csum[NN + i]);
}

// ---- K3 v11: DENSE MFMA, ALL-REGISTER, NO LDS, NO BARRIERS.
// Grid (64 m-blocks of 128, NCHUNK n-chunks), block 256 = 4 independent waves,
// each wave 32 m-rows x 512-n chunk, 16 steps. Per step:
//   B-frag: global uint4 at pt2[g][h][ft*16+col][4q..4q+3]  (L2-resident, coalesced)
//   A-frag: built in registers: lane(q,col) computes w[m=col][n=n0+8q+j] from
//           ntab + sorted bitmask word (bit = n&31) -> bf16x8 (m120 A-layout)
// Waves fully independent -> latency hidden by 4 waves/SIMD. Partials -> vpart. ----
__global__ __launch_bounds__(256, 2) void k_vals(const uint32_t* __restrict__ bitmask, const uint32_t* __restrict__ pt2,
                                                 const float4* __restrict__ ntab, const float* __restrict__ ss,
                                                 float* __restrict__ vpart) {
  const int t = threadIdx.x;
  const int lane = t & 63, wid = t >> 6;
  const int m0w = blockIdx.x * 128 + wid * 32;     // wave's 32 m-rows
  const int nc = blockIdx.y;
  const int q = lane >> 4, col = lane & 15;

  // ss for this lane's 2 m-frag rows (m = m0w + mf*16 + col), both heads
  float ss0[2], ss1[2];
#pragma unroll
  for (int mf = 0; mf < 2; ++mf) {
    ss0[mf] = ss[m0w + mf * 16 + col];
    ss1[mf] = ss[NN + m0w + mf * 16 + col];
  }

  f32x4 acc[2][8];
#pragma unroll
  for (int i = 0; i < 2; ++i)
#pragma unroll
    for (int j = 0; j < 8; ++j) acc[i][j] = (f32x4){0.f, 0.f, 0.f, 0.f};

  const uint32_t boff = (uint32_t)col * 16 + q * 4;   // word offset of this lane's B-frag

  for (int s = 0; s < 8192 / (32 * NCHUNK); ++s) {
    const int g = nc * (8192 / (32 * NCHUNK)) + s;    // 32-n group index
    const int n0 = g * 32;
    const uint32_t* gb = pt2 + (size_t)g * 4096 + boff;

    // ---- issue all 16 B loads (independent, L2) ----
    uint4 B0[8], B1[8];
#pragma unroll
    for (int ft = 0; ft < 8; ++ft) {
      B0[ft] = *(const uint4*)(gb + (ft * 16) * 16);
      B1[ft] = *(const uint4*)(gb + (128 + ft * 16) * 16);
    }

    // ---- build A-frags in registers (overlaps B latency) ----
    float4 tb[8];
#pragma unroll
    for (int j = 0; j < 8; ++j) tb[j] = ntab[n0 + q * 8 + j];
    uint32_t bw[2];
#pragma unroll
    for (int mf = 0; mf < 2; ++mf)
      bw[mf] = bitmask[(size_t)(m0w + mf * 16 + col) * 256 + g];

    bf16x8 A0[2], A1[2];   // [mf] for h0, h1
#pragma unroll
    for (int mf = 0; mf < 2; ++mf) {
      union { uint32_t w[4]; bf16x8 v; } a0u, a1u;
#pragma unroll
      for (int i = 0; i < 4; ++i) {
        float4 ta = tb[2 * i], tc = tb[2 * i + 1];
        bool b0 = (bw[mf] >> (q * 8 + 2 * i)) & 1;
        bool b1 = (bw[mf] >> (q * 8 + 2 * i + 1)) & 1;
        float w0a = __expf(lrelu(ss0[mf] + ta.x)) * ta.z;
        float w1a = __expf(lrelu(ss1[mf] + ta.y)) * ta.w;
        float w0b = __expf(lrelu(ss0[mf] + tc.x)) * tc.z;
        float w1b = __expf(lrelu(ss1[mf] + tc.y)) * tc.w;
        a0u.w[i] = bfpack(b0 ? w0a : 0.f, b1 ? w0b : 0.f);
        a1u.w[i] = bfpack(b0 ? w1a : 0.f, b1 ? w1b : 0.f);
      }
      A0[mf] = a0u.v; A1[mf] = a1u.v;
    }

    // ---- 32 MFMA ----
#pragma unroll
    for (int ft = 0; ft < 8; ++ft) {
      bf16x8 b0 = *(const bf16x8*)&B0[ft];
      acc[0][ft] = __builtin_amdgcn_mfma_f32_16x16x32_bf16(A0[0], b0, acc[0][ft], 0, 0, 0);
      acc[1][ft] = __builtin_amdgcn_mfma_f32_16x16x32_bf16(A0[1], b0, acc[1][ft], 0, 0, 0);
      bf16x8 b1 = *(const bf16x8*)&B1[ft];
      acc[0][ft] = __builtin_amdgcn_mfma_f32_16x16x32_bf16(A1[0], b1, acc[0][ft], 0, 0, 0);
      acc[1][ft] = __builtin_amdgcn_mfma_f32_16x16x32_bf16(A1[1], b1, acc[1][ft], 0, 0, 0);
    }
  }

  // ---- plain stores into private partial (head mean = x0.5) ----
  float* dst = vpart + (size_t)nc * NF;
#pragma unroll
  for (int mf = 0; mf < 2; ++mf)
#pragma unroll
    for (int ft = 0; ft < 8; ++ft)
#pragma unroll
      for (int r = 0; r < 4; ++r) {
        int mrow = m0w + mf * 16 + q * 4 + r;
        dst[mrow * FF + ft * 16 + col] = 0.5f * acc[mf][ft][r];
      }
}

// ---- K4: reduce NCHUNK partials -> vals + stats ----
__global__ __launch_bounds__(256) void k_stats(const float* __restrict__ vpart, float* __restrict__ vals,
                                               float* __restrict__ stats) {
  int i = (blockIdx.x * 256 + threadIdx.x) * 4;
  float4 a = make_float4(0.f, 0.f, 0.f, 0.f);
#pragma unroll
  for (int p = 0; p < NCHUNK; ++p) {
    float4 v = *(const float4*)&vpart[(size_t)p * NF + i];
    a.x += v.x; a.y += v.y; a.z += v.z; a.w += v.w;
  }
  *(float4*)&vals[i] = a;
  float s = a.x + a.y + a.z + a.w;
  float q = a.x * a.x + a.y * a.y + a.z * a.z + a.w * a.w;
#pragma unroll
  for (int o = 1; o < 64; o <<= 1) { s += __shfl_xor(s, o); q += __shfl_xor(q, o); }
  if ((threadIdx.x & 63) == 0) { atomicAdd(stats, s); atomicAdd(stats + 1, q); }
}

// ---- K5: instance-norm + residual + ELU ----
__global__ __launch_bounds__(256) void k_final(const float* __restrict__ vals, const float* __restrict__ resid,
                                               const float* __restrict__ stats, float* __restrict__ out) {
  int i = (blockIdx.x * 256 + threadIdx.x) * 4;
  float mu = stats[0] * (1.f / NF);
  float var = stats[1] * (1.f / NF) - mu * mu;
  float rs = rsqrtf(var + EPSI);
  float4 v = *(const float4*)&vals[i];
  float4 r = *(const float4*)&resid[i];
  float t0 = (v.x - mu) * rs + r.x;
  float t1 = (v.y - mu) * rs + r.y;
  float t2 = (v.z - mu) * rs + r.z;
  float t3 = (v.w - mu) * rs + r.w;
  float4 o;
  o.x = t0 > 0.f ? t0 : expm1f(t0);
  o.y = t1 > 0.f ? t1 : expm1f(t1);
  o.z = t2 > 0.f ? t2 : expm1f(t2);
  o.w = t3 > 0.f ? t3 : expm1f(t3);
  *(float4*)&out[i] = o;
}

extern "C" void kernel_launch(void* const* d_in, const int* in_sizes, int n_in,
                              void* d_out, int out_size, void* d_ws, size_t ws_size,
                              hipStream_t stream) {
  const float* x     = (const float*)d_in[0];
  const float* mask  = (const float*)d_in[1];
  const float* W     = (const float*)d_in[2];
  const float* a_src = (const float*)d_in[3];
  const float* a_tgt = (const float*)d_in[4];
  const float* wres  = (const float*)d_in[5];
  float* out = (float*)d_out;
  float* wsf = (float*)d_ws;

  float*    proj    = wsf + OFF_PROJ;
  uint32_t* bitmask = (uint32_t*)(wsf + OFF_PROJ);   // overlays proj after k_sprep
  float*    resid   = wsf + OFF_RESID;
  uint32_t* packed  = (uint32_t*)(wsf + OFF_PACKED);
  float*    ss      = wsf + OFF_SS;
  float*    st      = wsf + OFF_ST;
  float*    csum    = wsf + OFF_CSUM;
  float*    stats   = wsf + OFF_STATS;
  float4*   ntab    = (float4*)(wsf + OFF_NTAB);
  float*    vals    = wsf + OFF_VALS;
  float*    wt      = wsf + OFF_WT;
  uint32_t* pt2     = (uint32_t*)(wsf + OFF_PT2);
  float*    vpart   = wsf + OFF_VPART;

  (void)hipMemsetAsync(csum, 0, (2 * NN + 16) * sizeof(float), stream);

  hipLaunchKernelGGL(k_wt,    dim3(DIN * FF / 256), dim3(256), 0, stream, wres, wt);
  hipLaunchKernelGGL(k_gemm,  dim3(NN / 64, 3),     dim3(256), 0, stream, x, W, wt, proj, resid);
  hipLaunchKernelGGL(k_sprep, dim3(NN / 4),         dim3(256), 0, stream, proj, a_src, a_tgt, ss, st, packed);
  hipLaunchKernelGGL(k_tpose, dim3(NN / 32),        dim3(256), 0, stream, packed, pt2);
  hipLaunchKernelGGL(k_scan,  dim3(NN / 256, NN / 128), dim3(256), 0, stream, mask, out + NF, ss, st, csum, bitmask);
  hipLaunchKernelGGL(k_ntab,  dim3(NN / 256),       dim3(256), 0, stream, st, csum, ntab);
  hipLaunchKernelGGL(k_vals,  dim3(NN / 128, NCHUNK), dim3(256), 0, stream, bitmask, pt2, ntab, ss, vpart);
  hipLaunchKernelGGL(k_stats, dim3(NF / 1024),      dim3(256), 0, stream, vpart, vals, stats);
  hipLaunchKernelGGL(k_final, dim3(NF / 1024),      dim3(256), 0, stream, vals, resid, stats, out);
}

// Round 13
// 737.407 us; speedup vs baseline: 1.1321x; 1.1321x over previous
//
#include <hip/hip_runtime.h>
#include <stdint.h>

#define NN   8192
#define DIN  256
#define FF   128
#define NF   (NN*FF)          // 1048576
#define SLOPE 0.2f
#define EPSI  1e-5f
#define NCHUNK 8              // split-K chunks over n

typedef float vf4 __attribute__((ext_vector_type(4)));
typedef short bf16x8 __attribute__((ext_vector_type(8)));
typedef float f32x4 __attribute__((ext_vector_type(4)));

// ---- workspace layout (float offsets) ----
#define OFF_PROJ   0                       // [2][N][F] f32 (k_gemm->k_sprep), then REUSED as bitmask [N][256] u32 (8 MB)
#define OFF_RESID  (2*NF)                  // [N][F] f32
#define OFF_PACKED (3*NF)                  // [N][F] u32: lo16=bf16(h0), hi16=bf16(h1)
#define OFF_SS     (4*NF)                  // s_src [2][N]
#define OFF_ST     (OFF_SS + 2*NN)         // s_tgt [2][N]
#define OFF_CSUM   (OFF_ST + 2*NN)         // colsum [2][N]
#define OFF_STATS  (OFF_CSUM + 2*NN)       // S, SS (padded to 16)
#define OFF_NTAB   (OFF_STATS + 16)        // float4[N] = {st0, st1, rcp0, rcp1}
#define OFF_VALS   (OFF_NTAB + 4*NN)       // [N][F] f32
#define OFF_WT     (OFF_VALS + NF)         // W_res^T [DIN][F]
#define OFF_PT2    (OFF_WT + DIN*FF)       // packedT2: [N/32][2][128][16] u32 (4 MB)
#define OFF_VPART  (OFF_PT2 + NF)          // vpart: [NCHUNK][N][F] f32 (32 MB)

__device__ __forceinline__ float lrelu(float x) { return x >= 0.f ? x : SLOPE * x; }

__device__ __forceinline__ uint32_t bfpack(float a, float b) {
  uint32_t ua = __float_as_uint(a); ua += 0x7fffu + ((ua >> 16) & 1u);
  uint32_t ub = __float_as_uint(b); ub += 0x7fffu + ((ub >> 16) & 1u);
  return (ua >> 16) | (ub & 0xffff0000u);
}

// ---- K0: transpose W_res [F][DIN] -> Wt [DIN][F] ----
__global__ __launch_bounds__(256) void k_wt(const float* __restrict__ wres, float* __restrict__ wt) {
  int i = blockIdx.x * 256 + threadIdx.x;
  int d = i >> 7, f = i & 127;
  wt[i] = wres[f * DIN + d];
}

// ---- K1: 3 GEMMs M=8192 K=256 N=128 (heads 0,1 -> proj; y==2 -> resid) ----
__global__ __launch_bounds__(256) void k_gemm(const float* __restrict__ x, const float* __restrict__ Wh,
                                              const float* __restrict__ wt, float* __restrict__ proj,
                                              float* __restrict__ resid) {
  const int h = blockIdx.y;
  const float* __restrict__ Wsrc = (h < 2) ? (Wh + h * (DIN * FF)) : wt;
  float* __restrict__ outp = (h < 2) ? (proj + h * NF) : resid;
  const int row0 = blockIdx.x * 64;
  __shared__ float xs[64 * 68];
  const int tid = threadIdx.x;
  const int ft = tid & 15, rt = tid >> 4;
  const int f0 = ft * 8, r0 = rt * 4;
  float acc[4][8];
#pragma unroll
  for (int j = 0; j < 4; ++j)
#pragma unroll
    for (int k = 0; k < 8; ++k) acc[j][k] = 0.f;

  for (int kc = 0; kc < 4; ++kc) {
    const int d0 = kc * 64;
#pragma unroll
    for (int k2 = 0; k2 < 4; ++k2) {
      int i = tid * 4 + k2 * 1024;
      int r = i >> 6, dd = i & 63;
      *(float4*)&xs[r * 68 + dd] = *(const float4*)&x[(row0 + r) * DIN + d0 + dd];
    }
    __syncthreads();
#pragma unroll
    for (int g = 0; g < 16; ++g) {
      const int dd = g * 4;
      float xr[4][4];
#pragma unroll
      for (int j = 0; j < 4; ++j) {
        float4 t = *(const float4*)&xs[(r0 + j) * 68 + dd];
        xr[j][0] = t.x; xr[j][1] = t.y; xr[j][2] = t.z; xr[j][3] = t.w;
      }
#pragma unroll
      for (int i = 0; i < 4; ++i) {
        float4 wa = *(const float4*)&Wsrc[(d0 + dd + i) * FF + f0];
        float4 wb = *(const float4*)&Wsrc[(d0 + dd + i) * FF + f0 + 4];
#pragma unroll
        for (int j = 0; j < 4; ++j) {
          float xx = xr[j][i];
          acc[j][0] += xx * wa.x; acc[j][1] += xx * wa.y; acc[j][2] += xx * wa.z; acc[j][3] += xx * wa.w;
          acc[j][4] += xx * wb.x; acc[j][5] += xx * wb.y; acc[j][6] += xx * wb.z; acc[j][7] += xx * wb.w;
        }
      }
    }
    __syncthreads();
  }
#pragma unroll
  for (int j = 0; j < 4; ++j) {
    int row = row0 + r0 + j;
    *(float4*)&outp[row * FF + f0]     = make_float4(acc[j][0], acc[j][1], acc[j][2], acc[j][3]);
    *(float4*)&outp[row * FF + f0 + 4] = make_float4(acc[j][4], acc[j][5], acc[j][6], acc[j][7]);
  }
}

// ---- K1b: per-node dots s_src/s_tgt (both heads) + bf16 pack of proj ----
__global__ __launch_bounds__(256) void k_sprep(const float* __restrict__ proj, const float* __restrict__ a_src,
                                               const float* __restrict__ a_tgt, float* __restrict__ ss,
                                               float* __restrict__ st, uint32_t* __restrict__ packed) {
  int lane = threadIdx.x & 63, wid = threadIdx.x >> 6;
  int n = blockIdx.x * 4 + wid;
  float2 q0 = *(const float2*)&proj[n * FF + 2 * lane];
  float2 q1 = *(const float2*)&proj[NF + n * FF + 2 * lane];
  float2 as0 = *(const float2*)&a_src[2 * lane];
  float2 at0 = *(const float2*)&a_tgt[2 * lane];
  float2 as1 = *(const float2*)&a_src[FF + 2 * lane];
  float2 at1 = *(const float2*)&a_tgt[FF + 2 * lane];
  float v0 = q0.x * as0.x + q0.y * as0.y;
  float v1 = q0.x * at0.x + q0.y * at0.y;
  float v2 = q1.x * as1.x + q1.y * as1.y;
  float v3 = q1.x * at1.x + q1.y * at1.y;
#pragma unroll
  for (int o = 1; o < 64; o <<= 1) {
    v0 += __shfl_xor(v0, o); v1 += __shfl_xor(v1, o);
    v2 += __shfl_xor(v2, o); v3 += __shfl_xor(v3, o);
  }
  uint2 pk;
  pk.x = bfpack(q0.x, q1.x);
  pk.y = bfpack(q0.y, q1.y);
  *(uint2*)&packed[n * FF + 2 * lane] = pk;
  if (lane == 0) { ss[n] = v0; ss[NN + n] = v2; st[n] = v1; st[NN + n] = v3; }
}

// ---- K1c: packed[n][f] -> packedT2[n/32][h][f][n&31] bf16-pair words ----
__global__ __launch_bounds__(256) void k_tpose(const uint32_t* __restrict__ packed, uint32_t* __restrict__ pt2) {
  __shared__ uint32_t sb[32][129];
  const int t = threadIdx.x, c = blockIdx.x;
  const int nl = t >> 3, fb = (t & 7) * 16;
#pragma unroll
  for (int i = 0; i < 4; ++i) {
    uint4 v = *(const uint4*)&packed[(c * 32 + nl) * FF + fb + i * 4];
    sb[nl][fb + i * 4] = v.x; sb[nl][fb + i * 4 + 1] = v.y;
    sb[nl][fb + i * 4 + 2] = v.z; sb[nl][fb + i * 4 + 3] = v.w;
  }
  __syncthreads();
  const int h = t >> 7, f = t & 127;
  uint32_t wbuf[16];
#pragma unroll
  for (int p = 0; p < 16; ++p) {
    uint32_t a = sb[2 * p][f], b = sb[2 * p + 1][f];
    wbuf[p] = h ? ((a >> 16) | (b & 0xffff0000u)) : ((a & 0xffffu) | (b << 16));
  }
  uint32_t* dst = pt2 + ((c * 2 + h) * 128 + f) * 16;
#pragma unroll
  for (int i = 0; i < 4; ++i)
    *(uint4*)&dst[i * 4] = make_uint4(wbuf[i * 4], wbuf[i * 4 + 1], wbuf[i * 4 + 2], wbuf[i * 4 + 3]);
}

// ---- K2 v7 (k_scan): float4 loads + SORTED bitmask via nibble-butterfly.
// Block = 1024 cols x 64 rows, grid (8, 128). Per row: lane builds 4-bit edge
// nibble at position 4*(lane&7); shfl_xor-OR over strides 1,2,4 assembles the
// 32-col word; lanes &7==0 store 8 consecutive words (word = m*256 + n/32).
// colsum in registers, 8 atomics/thread at the end. ----
__global__ __launch_bounds__(256) void k_scan(const float* __restrict__ mask, float* __restrict__ maskout,
                                              const float* __restrict__ ss, const float* __restrict__ st,
                                              float* __restrict__ csum, uint32_t* __restrict__ bitmask) {
  const int tid = threadIdx.x;
  const int lane = tid & 63, wv = tid >> 6;
  const int nb = blockIdx.x * 1024 + tid * 4;          // thread's first column
  const int m0 = blockIdx.y * 64;
  const int wbase = blockIdx.x * 32 + wv * 8 + (lane >> 3);   // word index this lane-group stores
  const int sh = 4 * (lane & 7);
  const vf4 st0 = *(const vf4*)&st[nb];
  const vf4 st1 = *(const vf4*)&st[NN + nb];
  const float ssA = ss[m0 + lane];                     // head0, rows m0..m0+63
  const float ssC = ss[NN + m0 + lane];                // head1
  float c0[4] = {0.f, 0.f, 0.f, 0.f}, c1[4] = {0.f, 0.f, 0.f, 0.f};

  for (int i = 0; i < 64; i += 8) {
    vf4 v[8];
#pragma unroll
    for (int r = 0; r < 8; ++r)
      v[r] = __builtin_nontemporal_load((const vf4*)&mask[(size_t)(m0 + i + r) * NN + nb]);
#pragma unroll
    for (int r = 0; r < 8; ++r) {
      const int m = m0 + i + r;
      __builtin_nontemporal_store(v[r], (vf4*)&maskout[(size_t)m * NN + nb]);
      uint32_t x = ((v[r][0] > -0.5e9f ? 1u : 0u) | (v[r][1] > -0.5e9f ? 2u : 0u) |
                    (v[r][2] > -0.5e9f ? 4u : 0u) | (v[r][3] > -0.5e9f ? 8u : 0u)) << sh;
      x |= __shfl_xor(x, 1);
      x |= __shfl_xor(x, 2);
      x |= __shfl_xor(x, 4);                            // groups of 8 lanes share the word
      if ((lane & 7) == 0) bitmask[m * 256 + wbase] = x;
      const int ri = i + r;                             // uniform row index in [0,64)
      float s0 = __uint_as_float(__builtin_amdgcn_readlane(__float_as_uint(ssA), ri));
      float s1 = __uint_as_float(__builtin_amdgcn_readlane(__float_as_uint(ssC), ri));
#pragma unroll
      for (int j = 0; j < 4; ++j) {
        float w0 = __expf(lrelu(s0 + st0[j]));
        float w1 = __expf(lrelu(s1 + st1[j]));
        bool e = (x >> (sh + j)) & 1u;                  // own bits survive the OR
        c0[j] += e ? w0 : 0.f;
        c1[j] += e ? w1 : 0.f;
      }
    }
  }
#pragma unroll
  for (int j = 0; j < 4; ++j) {
    atomicAdd(&csum[nb + j], c0[j]);
    atomicAdd(&csum[NN + nb + j], c1[j]);
  }
}

// ---- K2c: pack per-column table {st0, st1, 1/csum0, 1/csum1} ----
__global__ __launch_bounds__(256) void k_ntab(const float* __restrict__ st, const float* __restrict__ csum,
                                              float4* __restrict__ ntab) {
  int i = blockIdx.x * 256 + threadIdx.x;
  ntab[i] = make_float4(st[i], st[NN + i], 1.f / csum[i], 1.f / csum[NN + i]);
}

// ---- K3 v10 (r11-verified, ~150us): DENSE MFMA, SPLIT-K into PRIVATE PARTIALS.
// Grid (128 m-tiles of 64, 8 n-chunks), block 128 (2 waves). LDS 24 KB.
// Fragment-ordered LDS: B2[h][ft][q][col][8], A2[h][mt][q][col][8] (lane-linear reads). ----
__global__ __launch_bounds__(128) void k_vals(const uint32_t* __restrict__ bitmask, const uint32_t* __restrict__ pt2,
                                              const float4* __restrict__ ntab, const float* __restrict__ ss,
                                              float* __restrict__ vpart) {
  __shared__ short B2[2][8][4][16][8];   // 16 KB
  __shared__ short A2[2][4][4][16][8];   //  8 KB (64 m-rows)
  const int t = threadIdx.x;
  const int lane = t & 63, wid = t >> 6;
  const int m0 = blockIdx.x * 64;
  const int nc = blockIdx.y;                   // n-chunk: 1024 n
  const int q = lane >> 4, col = lane & 15;
  const int n2 = t & 15, mg = t >> 4;          // A-build: n-pair, m-subgroup(0..7)

  float ssm0[8], ssm1[8];
#pragma unroll
  for (int p = 0; p < 8; ++p) {
    ssm0[p] = ss[m0 + mg + 8 * p];
    ssm1[p] = ss[NN + m0 + mg + 8 * p];
  }

  f32x4 acc[2][8];
#pragma unroll
  for (int i = 0; i < 2; ++i)
#pragma unroll
    for (int j = 0; j < 8; ++j) acc[i][j] = (f32x4){0.f, 0.f, 0.f, 0.f};

  uint32_t* B2w = (uint32_t*)&B2[0][0][0][0][0];
  uint32_t* A2w = (uint32_t*)&A2[0][0][0][0][0];

  for (int s = 0; s < 32; ++s) {
    const int n0 = nc * 1024 + s * 32;
    const uint32_t* src = pt2 + (nc * 32 + s) * 4096;   // [h][f][16 words]
#pragma unroll
    for (int h = 0; h < 2; ++h) {
      const uint4* p4 = (const uint4*)&src[(h * 128 + t) * 16];
#pragma unroll
      for (int k = 0; k < 4; ++k) {
        uint4 v = p4[k];
        *(uint4*)&B2w[(((h * 8 + (t >> 4)) * 4 + k) * 16 + (t & 15)) * 4] = v;
      }
    }
    float4 na = ntab[n0 + 2 * n2];
    float4 nb = ntab[n0 + 2 * n2 + 1];
#pragma unroll
    for (int p = 0; p < 8; ++p) {
      const int ml = mg + 8 * p;
      const int mt = ml >> 4, mcol = ml & 15;
      uint32_t bw = bitmask[(size_t)(m0 + ml) * 256 + (n0 >> 5)];
      float e0a = __expf(lrelu(ssm0[p] + na.x)) * na.z;
      float e1a = __expf(lrelu(ssm1[p] + na.y)) * na.w;
      float e0b = __expf(lrelu(ssm0[p] + nb.x)) * nb.z;
      float e1b = __expf(lrelu(ssm1[p] + nb.y)) * nb.w;
      bool b0 = (bw >> (2 * n2)) & 1, b1 = (bw >> (2 * n2 + 1)) & 1;
      e0a = b0 ? e0a : 0.f; e1a = b0 ? e1a : 0.f;
      e0b = b1 ? e0b : 0.f; e1b = b1 ? e1b : 0.f;
      int base = (mt * 4 + (n2 >> 2)) * 64 + mcol * 4 + (n2 & 3);
      A2w[base] = bfpack(e0a, e0b);
      A2w[base + 1024] = bfpack(e1a, e1b);     // h=1 plane = 4 mt * 4 q * 64 words
    }
    __syncthreads();
    bf16x8 a00 = *(const bf16x8*)&A2[0][wid * 2][q][col][0];
    bf16x8 a01 = *(const bf16x8*)&A2[0][wid * 2 + 1][q][col][0];
    bf16x8 a10 = *(const bf16x8*)&A2[1][wid * 2][q][col][0];
    bf16x8 a11 = *(const bf16x8*)&A2[1][wid * 2 + 1][q][col][0];
#pragma unroll
    for (int ft = 0; ft < 8; ++ft) {
      bf16x8 b0 = *(const bf16x8*)&B2[0][ft][q][col][0];
      acc[0][ft] = __builtin_amdgcn_mfma_f32_16x16x32_bf16(a00, b0, acc[0][ft], 0, 0, 0);
      acc[1][ft] = __builtin_amdgcn_mfma_f32_16x16x32_bf16(a01, b0, acc[1][ft], 0, 0, 0);
      bf16x8 b1 = *(const bf16x8*)&B2[1][ft][q][col][0];
      acc[0][ft] = __builtin_amdgcn_mfma_f32_16x16x32_bf16(a10, b1, acc[0][ft], 0, 0, 0);
      acc[1][ft] = __builtin_amdgcn_mfma_f32_16x16x32_bf16(a11, b1, acc[1][ft], 0, 0, 0);
    }
    __syncthreads();
  }

  float* dst = vpart + (size_t)nc * NF;
#pragma unroll
  for (int mt2 = 0; mt2 < 2; ++mt2)
#pragma unroll
    for (int ft = 0; ft < 8; ++ft)
#pragma unroll
      for (int r = 0; r < 4; ++r) {
        int mrow = m0 + (wid * 2 + mt2) * 16 + q * 4 + r;
        dst[mrow * FF + ft * 16 + col] = 0.5f * acc[mt2][ft][r];
      }
}

// ---- K4: reduce NCHUNK partials -> vals + stats ----
__global__ __launch_bounds__(256) void k_stats(const float* __restrict__ vpart, float* __restrict__ vals,
                                               float* __restrict__ stats) {
  int i = (blockIdx.x * 256 + threadIdx.x) * 4;
  float4 a = make_float4(0.f, 0.f, 0.f, 0.f);
#pragma unroll
  for (int p = 0; p < NCHUNK; ++p) {
    float4 v = *(const float4*)&vpart[(size_t)p * NF + i];
    a.x += v.x; a.y += v.y; a.z += v.z; a.w += v.w;
  }
  *(float4*)&vals[i] = a;
  float s = a.x + a.y + a.z + a.w;
  float q = a.x * a.x + a.y * a.y + a.z * a.z + a.w * a.w;
#pragma unroll
  for (int o = 1; o < 64; o <<= 1) { s += __shfl_xor(s, o); q += __shfl_xor(q, o); }
  if ((threadIdx.x & 63) == 0) { atomicAdd(stats, s); atomicAdd(stats + 1, q); }
}

// ---- K5: instance-norm + residual + ELU ----
__global__ __launch_bounds__(256) void k_final(const float* __restrict__ vals, const float* __restrict__ resid,
                                               const float* __restrict__ stats, float* __restrict__ out) {
  int i = (blockIdx.x * 256 + threadIdx.x) * 4;
  float mu = stats[0] * (1.f / NF);
  float var = stats[1] * (1.f / NF) - mu * mu;
  float rs = rsqrtf(var + EPSI);
  float4 v = *(const float4*)&vals[i];
  float4 r = *(const float4*)&resid[i];
  float t0 = (v.x - mu) * rs + r.x;
  float t1 = (v.y - mu) * rs + r.y;
  float t2 = (v.z - mu) * rs + r.z;
  float t3 = (v.w - mu) * rs + r.w;
  float4 o;
  o.x = t0 > 0.f ? t0 : expm1f(t0);
  o.y = t1 > 0.f ? t1 : expm1f(t1);
  o.z = t2 > 0.f ? t2 : expm1f(t2);
  o.w = t3 > 0.f ? t3 : expm1f(t3);
  *(float4*)&out[i] = o;
}

extern "C" void kernel_launch(void* const* d_in, const int* in_sizes, int n_in,
                              void* d_out, int out_size, void* d_ws, size_t ws_size,
                              hipStream_t stream) {
  const float* x     = (const float*)d_in[0];
  const float* mask  = (const float*)d_in[1];
  const float* W     = (const float*)d_in[2];
  const float* a_src = (const float*)d_in[3];
  const float* a_tgt = (const float*)d_in[4];
  const float* wres  = (const float*)d_in[5];
  float* out = (float*)d_out;
  float* wsf = (float*)d_ws;

  float*    proj    = wsf + OFF_PROJ;
  uint32_t* bitmask = (uint32_t*)(wsf + OFF_PROJ);   // overlays proj after k_sprep
  float*    resid   = wsf + OFF_RESID;
  uint32_t* packed  = (uint32_t*)(wsf + OFF_PACKED);
  float*    ss      = wsf + OFF_SS;
  float*    st      = wsf + OFF_ST;
  float*    csum    = wsf + OFF_CSUM;
  float*    stats   = wsf + OFF_STATS;
  float4*   ntab    = (float4*)(wsf + OFF_NTAB);
  float*    vals    = wsf + OFF_VALS;
  float*    wt      = wsf + OFF_WT;
  uint32_t* pt2     = (uint32_t*)(wsf + OFF_PT2);
  float*    vpart   = wsf + OFF_VPART;

  (void)hipMemsetAsync(csum, 0, (2 * NN + 16) * sizeof(float), stream);

  hipLaunchKernelGGL(k_wt,    dim3(DIN * FF / 256), dim3(256), 0, stream, wres, wt);
  hipLaunchKernelGGL(k_gemm,  dim3(NN / 64, 3),     dim3(256), 0, stream, x, W, wt, proj, resid);
  hipLaunchKernelGGL(k_sprep, dim3(NN / 4),         dim3(256), 0, stream, proj, a_src, a_tgt, ss, st, packed);
  hipLaunchKernelGGL(k_tpose, dim3(NN / 32),        dim3(256), 0, stream, packed, pt2);
  hipLaunchKernelGGL(k_scan,  dim3(NN / 1024, NN / 64), dim3(256), 0, stream, mask, out + NF, ss, st, csum, bitmask);
  hipLaunchKernelGGL(k_ntab,  dim3(NN / 256),       dim3(256), 0, stream, st, csum, ntab);
  hipLaunchKernelGGL(k_vals,  dim3(NN / 64, NCHUNK), dim3(128), 0, stream, bitmask, pt2, ntab, ss, vpart);
  hipLaunchKernelGGL(k_stats, dim3(NF / 1024),      dim3(256), 0, stream, vpart, vals, stats);
  hipLaunchKernelGGL(k_final, dim3(NF / 1024),      dim3(256), 0, stream, vals, resid, stats, out);
}